// Round 12
// baseline (1206.522 us; speedup 1.0000x reference)
//
#include <hip/hip_runtime.h>
#include <math.h>

#pragma clang fp contract(off)   // no implicit fusion; FMA only where ref has it

// Problem constants (fixed by the reference)
#define BB   8
#define NN   16384
#define FF   32
#define SS   2048
#define KK   32
#define OUTC 128

// force a value into uniform (SGPR) representation
__device__ __forceinline__ float uni(float v) {
    return __uint_as_float(__builtin_amdgcn_readfirstlane(__float_as_uint(v)));
}

// ---------------------------------------------------------------------------
// Reference-bit-exact fp32 helpers (validated R0-R7):
// x_sq / s_sq: numpy pairwise_sum scalar 8-accumulator block (n=32, no FMA)
__device__ __forceinline__ float np_sumsq32(const float* a) {
    float r[8];
#pragma unroll
    for (int j = 0; j < 8; j++) r[j] = a[j] * a[j];
#pragma unroll
    for (int t = 1; t < 4; t++) {
#pragma unroll
        for (int j = 0; j < 8; j++) {
            float e = a[8 * t + j] * a[8 * t + j];
            r[j] = r[j] + e;
        }
    }
    return ((r[0] + r[1]) + (r[2] + r[3])) + ((r[4] + r[5]) + (r[6] + r[7]));
}

// ---------------------------------------------------------------------------
// K1a: x_sq[b,n] = ref-order sum_f x^2
__global__ __launch_bounds__(256) void xsq_kernel(const float* __restrict__ x,
                                                  float* __restrict__ xsq) {
    int gid = blockIdx.x * 256 + threadIdx.x;      // < B*N
    const float4* r = (const float4*)(x + (size_t)gid * FF);
    float a[32];
#pragma unroll
    for (int j = 0; j < 8; j++) {
        float4 v = r[j];
        a[4 * j] = v.x; a[4 * j + 1] = v.y; a[4 * j + 2] = v.z; a[4 * j + 3] = v.w;
    }
    xsq[gid] = np_sumsq32(a);
}

// ---------------------------------------------------------------------------
// K1b: gather sampled features (row-major [B,S,F]) + ref-order s_sq
__global__ __launch_bounds__(256) void gather_kernel(const float* __restrict__ x,
                                                     const int* __restrict__ sidx,
                                                     float* __restrict__ sampled,
                                                     float* __restrict__ ssq) {
    int gid = blockIdx.x * 256 + threadIdx.x;      // < B*S
    int b = gid >> 11;
    int idx = sidx[gid];
    const float4* r = (const float4*)(x + ((size_t)b * NN + idx) * FF);
    float4* wo = (float4*)(sampled + (size_t)gid * FF);
    float a[32];
#pragma unroll
    for (int j = 0; j < 8; j++) {
        float4 v = r[j];
        a[4 * j] = v.x; a[4 * j + 1] = v.y; a[4 * j + 2] = v.z; a[4 * j + 3] = v.w;
        wo[j] = v;
    }
    ssq[gid] = np_sumsq32(a);
}

// ---------------------------------------------------------------------------
// K1c: sampled [B,S,F] -> output sampled_batch [B,F,S] (transpose via LDS)
__global__ __launch_bounds__(256) void transpose_kernel(const float* __restrict__ sampled,
                                                        float* __restrict__ out_samp) {
    __shared__ float tile[32][65];
    int b = blockIdx.x >> 5, sg = blockIdx.x & 31;
    int s0 = sg * 64;
    int tid = threadIdx.x;
    int f = tid & 31, si = tid >> 5;               // si in 0..7
#pragma unroll
    for (int r = 0; r < 8; r++) {
        int s = r * 8 + si;
        tile[f][s] = sampled[((size_t)b * SS + s0 + s) * FF + f];
    }
    __syncthreads();
#pragma unroll
    for (int r = 0; r < 8; r++) {
        int flat = r * 256 + tid;
        int fo = flat >> 6, sw = flat & 63;
        out_samp[((size_t)b * FF + fo) * SS + s0 + sw] = tile[fo][sw];
    }
}

// ---------------------------------------------------------------------------
// K2: per-point MLP, h2[b,n,:] = W2 @ relu(W1 @ x + b1) + b2  (fp32, VALU)
__global__ __launch_bounds__(256) void mlp_kernel(const float* __restrict__ x,
                                                  const float* __restrict__ W1,
                                                  const float* __restrict__ b1,
                                                  const float* __restrict__ W2,
                                                  const float* __restrict__ b2,
                                                  float* __restrict__ h2) {
    __shared__ float xs[64][36];          // padded
    __shared__ float hs[8512];            // h1t [128][65] then reused as h2s [64][133]
    int tid = threadIdx.x, lane = tid & 63;
    int wu = __builtin_amdgcn_readfirstlane(tid >> 6);
    size_t p0 = (size_t)blockIdx.x * 64;

    for (int i = tid; i < 64 * 8; i += 256) {
        int row = i >> 3, seg = i & 7;
        *(float4*)&xs[row][seg * 4] = *(const float4*)(x + (p0 + row) * FF + seg * 4);
    }
    __syncthreads();

    float xr[32];
    {
        const float4* r = (const float4*)&xs[lane][0];
#pragma unroll
        for (int j = 0; j < 8; j++) {
            float4 v = r[j];
            xr[4 * j] = v.x; xr[4 * j + 1] = v.y; xr[4 * j + 2] = v.z; xr[4 * j + 3] = v.w;
        }
    }
#pragma unroll 4
    for (int i = 0; i < 32; i++) {
        int o = wu * 32 + i;
        const float4* wr = (const float4*)(W1 + o * FF);
        float a = b1[o];
#pragma unroll
        for (int j = 0; j < 8; j++) {
            float4 v = wr[j];
            a = fmaf(v.x, xr[4 * j], a);     a = fmaf(v.y, xr[4 * j + 1], a);
            a = fmaf(v.z, xr[4 * j + 2], a); a = fmaf(v.w, xr[4 * j + 3], a);
        }
        hs[o * 65 + lane] = fmaxf(a, 0.f);
    }
    __syncthreads();
    float acc[32];
#pragma unroll
    for (int i = 0; i < 32; i++) acc[i] = b2[wu * 32 + i];
    for (int k4 = 0; k4 < 32; k4++) {
        float h0 = hs[(4 * k4 + 0) * 65 + lane];
        float h1v = hs[(4 * k4 + 1) * 65 + lane];
        float h2v = hs[(4 * k4 + 2) * 65 + lane];
        float h3v = hs[(4 * k4 + 3) * 65 + lane];
#pragma unroll
        for (int i = 0; i < 32; i++) {
            const float4 v = *(const float4*)(W2 + (wu * 32 + i) * OUTC + 4 * k4);
            acc[i] = fmaf(v.x, h0, acc[i]);  acc[i] = fmaf(v.y, h1v, acc[i]);
            acc[i] = fmaf(v.z, h2v, acc[i]); acc[i] = fmaf(v.w, h3v, acc[i]);
        }
    }
    __syncthreads();
#pragma unroll 4
    for (int i = 0; i < 32; i++) hs[lane * 133 + wu * 32 + i] = acc[i];
    __syncthreads();
    for (int j = 0; j < 32; j++) {
        int flat = j * 256 + tid;
        int p = flat >> 7, o = flat & 127;
        h2[(p0 + p) * OUTC + o] = hs[p * 133 + o];
    }
}

// ---------------------------------------------------------------------------
// K3 v6: 4 queries/wave (q0,q1 SGPR; q2,q3 VGPR) in the LOW-PRESSURE R9
// structure: simple two-barrier staging, no long-lived prefetch registers,
// launch_bounds(256,2) so the allocator is never forced to spill.
__device__ __forceinline__ bool lessp(float da, int ia, float db, int ib) {
    return da < db || (da == db && ia < ib);
}
__device__ __forceinline__ void cswap(float& d, int& i, int j, bool dirAsc, int lane) {
    float od = __shfl_xor(d, j);
    int   oi = __shfl_xor(i, j);
    bool lower = (lane & j) == 0;
    bool oLess = lessp(od, oi, d, i);
    if (oLess == (lower == dirAsc)) { d = od; i = oi; }
}
__device__ __forceinline__ void sort64(float& d, int& i, bool asc, int lane) {
#pragma unroll
    for (int k = 2; k <= 64; k <<= 1) {
        bool ba = (((lane & k) == 0) == asc);
#pragma unroll
        for (int j = k >> 1; j > 0; j >>= 1) cswap(d, i, j, ba, lane);
    }
}
// sort m valid slots, keep lowest-64 lex-sorted in [0,64); return 32nd-smallest
__device__ __forceinline__ float wave_compact2(float* bd, int* bi, int m, int lane) {
    float d0 = (lane < m) ? bd[lane] : INFINITY;
    int   i0 = (lane < m) ? bi[lane] : 0x7fffffff;
    float d1 = (lane + 64 < m) ? bd[lane + 64] : INFINITY;
    int   i1 = (lane + 64 < m) ? bi[lane + 64] : 0x7fffffff;
    sort64(d0, i0, true, lane);
    sort64(d1, i1, false, lane);
    bool t = lessp(d1, i1, d0, i0);
    float ld = t ? d1 : d0;
    int   li = t ? i1 : i0;
#pragma unroll
    for (int j = 32; j > 0; j >>= 1) cswap(ld, li, j, true, lane);
    bd[lane] = ld; bi[lane] = li;
    return uni(__shfl(ld, 31));            // uniform across wave
}
__device__ __forceinline__ void insert_cand(float dv, int n, int lane,
                                            float* bd, int* bi,
                                            int& cnt, float& tau) {
    unsigned long long m = __ballot(dv < tau);
    if (m) {                               // wave-uniform branch
        int pos = cnt + __builtin_popcountll(m & ((1ull << lane) - 1ull));
        if (dv < tau) { bd[pos] = dv; bi[pos] = n; }
        cnt += __builtin_popcountll(m);
        if (cnt > 64) { tau = wave_compact2(bd, bi, cnt, lane); cnt = 32; }
    }
}

__global__ __launch_bounds__(256, 2) void topk_kernel(const float* __restrict__ x,
                                                      const float* __restrict__ x_sq,
                                                      const float* __restrict__ sampled,
                                                      const float* __restrict__ s_sq,
                                                      int* __restrict__ nbr) {
    int b = blockIdx.x & 7;                 // XCD-by-batch swizzle
    int qg = blockIdx.x >> 3;               // 0..127
    int tid = threadIdx.x, lane = tid & 63;
    int w = __builtin_amdgcn_readfirstlane(tid >> 6);
    __shared__ float xs[64][36];            // single buffer, padded rows
    __shared__ float bufd[16][128];
    __shared__ int   bufi[16][128];
    int s0 = qg * 16;                       // 16 queries per block, 4 per wave
    const float* xb = x + (size_t)b * (NN * FF);
    const float* xqb = x_sq + (size_t)b * NN;

    // 4 query feature vectors: q0,q1 -> SGPRs (uni); q2,q3 -> VGPRs
    float sa0[32], sa1[32], sa2[32], sa3[32];
    {
        const float* sp = sampled + ((size_t)b * SS + s0 + w * 4) * FF;
#pragma unroll
        for (int k = 0; k < 32; k++) {
            sa0[k] = uni(sp[k]);
            sa1[k] = uni(sp[FF + k]);
            sa2[k] = sp[2 * FF + k];
            sa3[k] = sp[3 * FF + k];
        }
    }
    float ssq0 = uni(s_sq[b * SS + s0 + w * 4 + 0]);
    float ssq1 = uni(s_sq[b * SS + s0 + w * 4 + 1]);
    float ssq2 = s_sq[b * SS + s0 + w * 4 + 2];
    float ssq3 = s_sq[b * SS + s0 + w * 4 + 3];

    float* bq0d = &bufd[w * 4 + 0][0];  int* bq0i = &bufi[w * 4 + 0][0];
    float* bq1d = &bufd[w * 4 + 1][0];  int* bq1i = &bufi[w * 4 + 1][0];
    float* bq2d = &bufd[w * 4 + 2][0];  int* bq2i = &bufi[w * 4 + 2][0];
    float* bq3d = &bufd[w * 4 + 3][0];  int* bq3i = &bufi[w * 4 + 3][0];
    int   cnt0 = 0, cnt1 = 0, cnt2 = 0, cnt3 = 0;      // wave-uniform
    float tau0 = INFINITY, tau1 = INFINITY, tau2 = INFINITY, tau3 = INFINITY;

    for (int t = 0; t < NN / 64; t++) {
        int n0 = t * 64;
        __syncthreads();
        for (int i = tid; i < 512; i += 256) {
            int row = i >> 3, seg = i & 7;
            *(float4*)&xs[row][seg * 4] = *(const float4*)(xb + (size_t)(n0 + row) * FF + (seg << 2));
        }
        __syncthreads();

        int n = n0 + lane;
        float xq = xqb[n];                  // coalesced, L2-hot
        // 4 dot chains interleaved; ref-exact sequential FMA order each.
        float c0 = 0.f, c1 = 0.f, c2 = 0.f, c3 = 0.f;
        {
            const float4* rr = (const float4*)&xs[lane][0];
#pragma unroll
            for (int j = 0; j < 8; j++) {
                float4 v = rr[j];
                c0 = fmaf(sa0[4 * j], v.x, c0);     c1 = fmaf(sa1[4 * j], v.x, c1);
                c2 = fmaf(sa2[4 * j], v.x, c2);     c3 = fmaf(sa3[4 * j], v.x, c3);
                c0 = fmaf(sa0[4 * j + 1], v.y, c0); c1 = fmaf(sa1[4 * j + 1], v.y, c1);
                c2 = fmaf(sa2[4 * j + 1], v.y, c2); c3 = fmaf(sa3[4 * j + 1], v.y, c3);
                c0 = fmaf(sa0[4 * j + 2], v.z, c0); c1 = fmaf(sa1[4 * j + 2], v.z, c1);
                c2 = fmaf(sa2[4 * j + 2], v.z, c2); c3 = fmaf(sa3[4 * j + 2], v.z, c3);
                c0 = fmaf(sa0[4 * j + 3], v.w, c0); c1 = fmaf(sa1[4 * j + 3], v.w, c1);
                c2 = fmaf(sa2[4 * j + 3], v.w, c2); c3 = fmaf(sa3[4 * j + 3], v.w, c3);
            }
        }
        float d0v = (ssq0 + xq) - (c0 + c0);   // ref combine order
        float d1v = (ssq1 + xq) - (c1 + c1);
        float d2v = (ssq2 + xq) - (c2 + c2);
        float d3v = (ssq3 + xq) - (c3 + c3);

        insert_cand(d0v, n, lane, bq0d, bq0i, cnt0, tau0);
        insert_cand(d1v, n, lane, bq1d, bq1i, cnt1, tau1);
        insert_cand(d2v, n, lane, bq2d, bq2i, cnt2, tau2);
        insert_cand(d3v, n, lane, bq3d, bq3i, cnt3, tau3);
    }
    // final: compact (lex-sorts survivors) and emit first 32 per query
    wave_compact2(bq0d, bq0i, cnt0, lane);
    wave_compact2(bq1d, bq1i, cnt1, lane);
    wave_compact2(bq2d, bq2i, cnt2, lane);
    wave_compact2(bq3d, bq3i, cnt3, lane);
    int s = s0 + w * 4;
    if (lane < 32) {
        nbr[((size_t)b * SS + s + 0) * KK + lane] = bq0i[lane];
        nbr[((size_t)b * SS + s + 1) * KK + lane] = bq1i[lane];
        nbr[((size_t)b * SS + s + 2) * KK + lane] = bq2i[lane];
        nbr[((size_t)b * SS + s + 3) * KK + lane] = bq3i[lane];
    }
}

// ---------------------------------------------------------------------------
// K4: features_batch[b,o,s] = max_k h2[b, nbr[b,s,k], o]; block=128, 16 s/block
__global__ __launch_bounds__(128) void maxgather_kernel(const float* __restrict__ h2,
                                                        const int* __restrict__ nbr,
                                                        float* __restrict__ out_feat) {
    __shared__ float fs[128][17];
    int b = blockIdx.x & 7;
    int sg = blockIdx.x >> 3;               // 0..127
    int s0 = sg * 16;
    int tid = threadIdx.x;                  // o = tid (0..127)
    for (int si = 0; si < 16; si++) {
        int s = s0 + si;
        const int* row = nbr + ((size_t)b * SS + s) * KK;
        float m = -INFINITY;
#pragma unroll 4
        for (int k = 0; k < KK; k++) {
            int idx = row[k];
            float v = h2[((size_t)b * NN + idx) * OUTC + tid];
            m = fmaxf(m, v);
        }
        fs[tid][si] = m;
    }
    __syncthreads();
#pragma unroll
    for (int j = 0; j < 16; j++) {
        int flat = j * 128 + tid;
        int fo = flat >> 4, sw = flat & 15;
        out_feat[((size_t)b * OUTC + fo) * SS + s0 + sw] = fs[fo][sw];
    }
}

// ---------------------------------------------------------------------------
extern "C" void kernel_launch(void* const* d_in, const int* in_sizes, int n_in,
                              void* d_out, int out_size, void* d_ws, size_t ws_size,
                              hipStream_t stream) {
    const float* x    = (const float*)d_in[0];
    const int*   sidx = (const int*)d_in[1];
    const float* W1   = (const float*)d_in[2];
    const float* b1   = (const float*)d_in[3];
    const float* W2   = (const float*)d_in[4];
    const float* b2   = (const float*)d_in[5];

    float* out_feat = (float*)d_out;                       // [B,128,S]
    float* out_samp = out_feat + (size_t)BB * OUTC * SS;   // [B,32,S]

    float* h2      = (float*)d_ws;                         // B*N*128 fp32 = 64 MB
    float* sampled = h2 + (size_t)BB * NN * OUTC;          // B*S*F
    float* xsq     = sampled + (size_t)BB * SS * FF;       // B*N
    float* ssq     = xsq + (size_t)BB * NN;                // B*S
    int*   nbr     = (int*)(ssq + (size_t)BB * SS);        // B*S*K

    xsq_kernel<<<dim3(BB * NN / 256), dim3(256), 0, stream>>>(x, xsq);
    gather_kernel<<<dim3(BB * SS / 256), dim3(256), 0, stream>>>(x, sidx, sampled, ssq);
    mlp_kernel<<<dim3(BB * NN / 64), dim3(256), 0, stream>>>(x, W1, b1, W2, b2, h2);
    transpose_kernel<<<dim3(BB * SS / 64), dim3(256), 0, stream>>>(sampled, out_samp);
    topk_kernel<<<dim3(BB * SS / 16), dim3(256), 0, stream>>>(x, xsq, sampled, ssq, nbr);
    maxgather_kernel<<<dim3(BB * SS / 16), dim3(128), 0, stream>>>(h2, nbr, out_feat);
}